// Round 4
// baseline (389.855 us; speedup 1.0000x reference)
//
#include <hip/hip_runtime.h>

#define N_NODES 50000
#define D       256
#define E_EDGES 400000
#define LN_EPS  1e-5f

// ---- two-level counting sort geometry (key = 3*dst + r) ----
#define NPB     25                                  // nodes per fine bin
#define BPB     (3 * NPB)                           // 75 buckets per bin
#define NCB     (N_NODES / NPB)                     // 2000 fine bins (exact)
#define EPB     2000                                // edges per hist/scatter block
#define RB_PER  (E_EDGES / EPB)                     // 200 blocks per relation
#define NBA     (3 * RB_PER)                        // 600 hist/scatter blocks
#define GHN     (NCB * NBA)                         // 1.2M scan elements
#define GH_NB   ((GHN + 1023) / 1024)               // 1172 scan chunks
#define CMAX    1024                                // bin record capacity (mean 600, +17 sigma)

#define GB_ROWS 64
#define GEMM_NB ((N_NODES + GB_ROWS - 1) / GB_ROWS) // 782

typedef __attribute__((ext_vector_type(8))) short bf16x8;
typedef __attribute__((ext_vector_type(4))) float f32x4;
typedef __attribute__((ext_vector_type(2))) float f32x2;

__device__ __forceinline__ unsigned short f2bf(float f) {
    unsigned int x = __float_as_uint(f);
    x += 0x7fffu + ((x >> 16) & 1u);     // RNE
    return (unsigned short)(x >> 16);
}
__device__ __forceinline__ unsigned int pack2(float lo, float hi) {
    return (unsigned int)f2bf(lo) | ((unsigned int)f2bf(hi) << 16);
}

// ---------------------------------------------------------------------------
// K1: blocks [0,256): Wt[n][k] = bf16((W0+W1+W2)[k][n]/3) (MFMA B^T) + flag=0
//     blocks [256,856): coarse histogram — LDS atomics over 2000 bins
//     (bin = dst/25; all 3 relations of a node share a bin), write
//     ghist[bin*NBA + blk].  ZERO global atomics.
// (softmax of size-1 tensors == 1; softmax([1,1,1]) == exactly 1/3 each)
// ---------------------------------------------------------------------------
__global__ __launch_bounds__(256) void k_prep2(const float* __restrict__ W0,
                                               const float* __restrict__ W1,
                                               const float* __restrict__ W2,
                                               unsigned short* __restrict__ Wt,
                                               int* __restrict__ flag,
                                               const int* __restrict__ dst0,
                                               const int* __restrict__ dst1,
                                               const int* __restrict__ dst2,
                                               int* __restrict__ ghist) {
    __shared__ int hist[NCB];
    const int b = blockIdx.x, t = threadIdx.x;
    if (b < 256) {
        if (b == 0 && t == 0) flag[0] = 0;
        int i = b * 256 + t;                 // i = n*256 + k
        int n = i >> 8, k = i & 255;
        float v = (W0[k * D + n] + W1[k * D + n] + W2[k * D + n]) * (1.0f / 3.0f);
        Wt[i] = f2bf(v);
        return;
    }
    const int hb = b - 256;                  // 0..599
    for (int i = t; i < NCB; i += 256) hist[i] = 0;
    __syncthreads();
    const int r = hb / RB_PER, rb = hb - r * RB_PER;
    const int4* dq = (const int4*)((r == 0) ? dst0 : (r == 1) ? dst1 : dst2);
    const int qb = rb * (EPB / 4);
#pragma unroll
    for (int it = 0; it < 2; ++it) {
        int q = t + it * 256;
        if (q < EPB / 4) {
            int4 d = dq[qb + q];
            atomicAdd(&hist[d.x / NPB], 1);
            atomicAdd(&hist[d.y / NPB], 1);
            atomicAdd(&hist[d.z / NPB], 1);
            atomicAdd(&hist[d.w / NPB], 1);
        }
    }
    __syncthreads();
    for (int i = t; i < NCB; i += 256) ghist[i * NBA + hb] = hist[i];
}

// ---------------------------------------------------------------------------
// K2: blocks [0, GH_NB): two-level scan of ghist (R6-proven pattern;
//     chunk-local values stay in g, chunk bases in csum via last block).
//     blocks [GH_NB, +GEMM_NB): MFMA GEMM h = bf16(feat) @ Wt^T with
//     LDS-staged B (R3-proven: K-tiled BK=64, +8 pad, coalesced staging).
// ---------------------------------------------------------------------------
__global__ __launch_bounds__(256, 3) void k_scan_gemm(int* __restrict__ g,
                                                      int* __restrict__ csum,
                                                      int* __restrict__ flag,
                                                      const float* __restrict__ feat,
                                                      const unsigned short* __restrict__ Wt,
                                                      unsigned short* __restrict__ h) {
    __shared__ unsigned short sB[256][72];   // 36864 B: Wt[0:256][k0:k0+64)
    __shared__ unsigned short sAk[64][72];   //  9216 B: bf16 A slice
    __shared__ int wsum[4];
    __shared__ int amLast;
    const int b = blockIdx.x, t = threadIdx.x;
    const int lane = t & 63;

    if (b < GH_NB) {
        const int base = b * 1024 + t * 4;
        int4 v = make_int4(0, 0, 0, 0);
        if (base < GHN) v = *(const int4*)(g + base);   // GHN % 4 == 0
        const int s1 = v.x + v.y, s2 = s1 + v.z, s3 = s2 + v.w;
        int x = s3;
#pragma unroll
        for (int o2 = 1; o2 < 64; o2 <<= 1) {
            int y = __shfl_up(x, o2, 64);
            if (lane >= o2) x += y;
        }
        if (lane == 63) wsum[t >> 6] = x;
        const int texcl = x - s3;
        __syncthreads();
        int wb = 0;
#pragma unroll
        for (int wi = 0; wi < 4; ++wi)
            if (wi < (t >> 6)) wb += wsum[wi];
        const int ex = wb + texcl;
        if (base < GHN) {
            int4 o4 = make_int4(ex, ex + v.x, ex + s1, ex + s2);
            *(int4*)(g + base) = o4;
        }
        if (t == 0) csum[b] = wsum[0] + wsum[1] + wsum[2] + wsum[3];
        __threadfence();
        if (t == 0) amLast = (atomicAdd(flag, 1) == GH_NB - 1);
        __syncthreads();
        if (!amLast) return;
        __threadfence();
        int carry = 0;
        for (int r0 = 0; r0 < GH_NB; r0 += 256) {
            int idx = r0 + t;
            int vv = (idx < GH_NB) ? ((volatile int*)csum)[idx] : 0;
            int x2 = vv;
#pragma unroll
            for (int o2 = 1; o2 < 64; o2 <<= 1) {
                int y = __shfl_up(x2, o2, 64);
                if (lane >= o2) x2 += y;
            }
            if (lane == 63) wsum[t >> 6] = x2;
            __syncthreads();
            int wb2 = 0;
#pragma unroll
            for (int wi = 0; wi < 4; ++wi)
                if (wi < (t >> 6)) wb2 += wsum[wi];
            int tot = wsum[0] + wsum[1] + wsum[2] + wsum[3];
            if (idx < GH_NB) csum[idx] = carry + wb2 + x2 - vv;
            carry += tot;
            __syncthreads();
        }
        return;
    }

    // ---- GEMM path: K-tiled, LDS-staged B (R3-proven verbatim) ----
    const int row0 = (b - GH_NB) * GB_ROWS;
    const float4* feat4 = (const float4*)feat;
    const int w  = t >> 6;
    const int lr = lane & 15;
    const int lq = lane >> 4;
    const int ar  = t >> 2, aseg = t & 3;    // A staging: 64 rows x 4 segs

    f32x4 acc[16];
#pragma unroll
    for (int tt = 0; tt < 16; ++tt) acc[tt] = (f32x4){0.f, 0.f, 0.f, 0.f};

#pragma unroll
    for (int ks2 = 0; ks2 < 4; ++ks2) {
        if (ks2) __syncthreads();            // protect prev-tile reads
#pragma unroll
        for (int i = 0; i < 8; ++i) {
            int chunk = i * 256 + t;         // 0..2047
            int n = chunk >> 3, c = chunk & 7;
            uint4 v = *(const uint4*)(Wt + n * 256 + ks2 * 64 + c * 8);
            *(uint4*)&sB[n][c * 8] = v;
        }
        {
            float4 a0 = make_float4(0.f, 0.f, 0.f, 0.f), a1 = a0, a2 = a0, a3 = a0;
            if (row0 + ar < N_NODES) {
                const float4* fp = feat4 + (size_t)(row0 + ar) * 64 + ks2 * 16 + aseg * 4;
                a0 = fp[0]; a1 = fp[1]; a2 = fp[2]; a3 = fp[3];
            }
            uint4 p0, p1;
            p0.x = pack2(a0.x, a0.y); p0.y = pack2(a0.z, a0.w);
            p0.z = pack2(a1.x, a1.y); p0.w = pack2(a1.z, a1.w);
            p1.x = pack2(a2.x, a2.y); p1.y = pack2(a2.z, a2.w);
            p1.z = pack2(a3.x, a3.y); p1.w = pack2(a3.z, a3.w);
            *(uint4*)&sAk[ar][aseg * 16]     = p0;
            *(uint4*)&sAk[ar][aseg * 16 + 8] = p1;
        }
        __syncthreads();
#pragma unroll
        for (int kk = 0; kk < 2; ++kk) {
            bf16x8 af = *(const bf16x8*)&sAk[w * 16 + lr][kk * 32 + lq * 8];
            bf16x8 bfr[16];
#pragma unroll
            for (int tt = 0; tt < 16; ++tt)
                bfr[tt] = *(const bf16x8*)&sB[tt * 16 + lr][kk * 32 + lq * 8];
#pragma unroll
            for (int tt = 0; tt < 16; ++tt)
                acc[tt] = __builtin_amdgcn_mfma_f32_16x16x32_bf16(af, bfr[tt], acc[tt], 0, 0, 0);
        }
    }

    __syncthreads();
    unsigned short* sC = &sB[0][0];          // 64 x 264 = 33792 ushorts <= sB
#pragma unroll
    for (int tt = 0; tt < 16; ++tt) {
#pragma unroll
        for (int j = 0; j < 4; ++j)
            sC[(w * 16 + lq * 4 + j) * 264 + tt * 16 + lr] = f2bf(acc[tt][j]);
    }
    __syncthreads();

#pragma unroll
    for (int i = 0; i < 8; ++i) {
        int c = i * 256 + t;
        int r = c >> 5, cc = c & 31;
        if (row0 + r < N_NODES) {
            uint4 v = *(const uint4*)&sC[r * 264 + cc * 8];
            *(uint4*)(h + (size_t)(row0 + r) * D + cc * 8) = v;
        }
    }
}

// ---------------------------------------------------------------------------
// K3: coarse scatter.  Per-block LDS base table sbase[bin]; LDS atomicAdd
// returns dense global positions.  Record = (fineKey<<16) | src where
// fineKey = 3*(dst%25)+r < 75, src < 65536.  ZERO global atomics.
// ---------------------------------------------------------------------------
__global__ __launch_bounds__(256) void k_scatter(const int* __restrict__ src0,
                                                 const int* __restrict__ dst0,
                                                 const int* __restrict__ src1,
                                                 const int* __restrict__ dst1,
                                                 const int* __restrict__ src2,
                                                 const int* __restrict__ dst2,
                                                 const int* __restrict__ g,
                                                 const int* __restrict__ csum,
                                                 unsigned int* __restrict__ coarse) {
    __shared__ int sbase[NCB];
    const int b = blockIdx.x, t = threadIdx.x;
    for (int i = t; i < NCB; i += 256) {
        int j = i * NBA + b;
        sbase[i] = g[j] + csum[j >> 10];
    }
    __syncthreads();
    const int r = b / RB_PER, rb = b - r * RB_PER;
    const int4* sq = (const int4*)((r == 0) ? src0 : (r == 1) ? src1 : src2);
    const int4* dq = (const int4*)((r == 0) ? dst0 : (r == 1) ? dst1 : dst2);
    const int qb = rb * (EPB / 4);
#pragma unroll
    for (int it = 0; it < 2; ++it) {
        int q = t + it * 256;
        if (q < EPB / 4) {
            int4 s = sq[qb + q];
            int4 d = dq[qb + q];
            int bin, p;
            bin = d.x / NPB; p = atomicAdd(&sbase[bin], 1);
            coarse[p] = ((unsigned)(3 * (d.x - bin * NPB) + r) << 16) | (unsigned)s.x;
            bin = d.y / NPB; p = atomicAdd(&sbase[bin], 1);
            coarse[p] = ((unsigned)(3 * (d.y - bin * NPB) + r) << 16) | (unsigned)s.y;
            bin = d.z / NPB; p = atomicAdd(&sbase[bin], 1);
            coarse[p] = ((unsigned)(3 * (d.z - bin * NPB) + r) << 16) | (unsigned)s.z;
            bin = d.w / NPB; p = atomicAdd(&sbase[bin], 1);
            coarse[p] = ((unsigned)(3 * (d.w - bin * NPB) + r) << 16) | (unsigned)s.w;
        }
    }
}

// ---------------------------------------------------------------------------
// K4: fused fine-CSR + gather + ReLU + LayerNorm.  One block per fine bin
// (25 nodes, 75 buckets, ~600 records): build the bin's CSR entirely in LDS
// (histogram-with-rank + wave scan + LDS edge list), then 4 waves gather the
// 25 nodes' h rows (proven half-wave uint4 pair scheme) and write LN output.
// eidx/deg/off never touch global memory.
// ---------------------------------------------------------------------------
__device__ __forceinline__ void pair_acc(const uint4* __restrict__ h4, int sa, int sb,
                                         int half, int cl,
                                         f32x2& a0, f32x2& a1, f32x2& a2, f32x2& a3) {
    int su = half ? sb : sa;
    uint4 u = h4[(size_t)su * 32 + cl];
    f32x2 v;
    v.x = __uint_as_float(u.x << 16); v.y = __uint_as_float(u.x & 0xffff0000u); a0 += v;
    v.x = __uint_as_float(u.y << 16); v.y = __uint_as_float(u.y & 0xffff0000u); a1 += v;
    v.x = __uint_as_float(u.z << 16); v.y = __uint_as_float(u.z & 0xffff0000u); a2 += v;
    v.x = __uint_as_float(u.w << 16); v.y = __uint_as_float(u.w & 0xffff0000u); a3 += v;
}

__global__ __launch_bounds__(256) void k_fine_gather(const unsigned int* __restrict__ coarse,
                                                     const int* __restrict__ g,
                                                     const int* __restrict__ csum,
                                                     const unsigned short* __restrict__ h,
                                                     const float* __restrict__ gamma,
                                                     const float* __restrict__ beta,
                                                     float* __restrict__ out) {
    __shared__ int fh[80], fb[80];
    __shared__ unsigned short eidxL[CMAX];
    const int c = blockIdx.x, t = threadIdx.x;
    const int lane = t & 63, w = t >> 6;
    const int j0 = c * NBA;
    const int S = g[j0] + csum[j0 >> 10];
    const int E = (c + 1 < NCB) ? (g[j0 + NBA] + csum[(j0 + NBA) >> 10]) : (3 * E_EDGES);
    int cnt = E - S;
    if (cnt > CMAX) cnt = CMAX;              // 17-sigma guard vs LDS overflow
    if (t < 80) fh[t] = 0;
    __syncthreads();

    unsigned int recs[4];
    int lrk[4];
#pragma unroll
    for (int it = 0; it < 4; ++it) {
        int i = t + it * 256;
        recs[it] = 0; lrk[it] = 0;
        if (i < cnt) {
            unsigned int rec = coarse[S + i];
            recs[it] = rec;
            lrk[it] = atomicAdd(&fh[rec >> 16], 1);
        }
    }
    __syncthreads();
    if (t < 64) {                            // wave-0 exclusive scan of 75 counts
        int carry = 0;
        for (int b2 = 0; b2 < BPB; b2 += 64) {
            int idx = b2 + t;
            int v = (idx < BPB) ? fh[idx] : 0;
            int x = v;
#pragma unroll
            for (int o2 = 1; o2 < 64; o2 <<= 1) {
                int y = __shfl_up(x, o2, 64);
                if (t >= o2) x += y;
            }
            if (idx < BPB) fb[idx] = carry + x - v;
            carry += __shfl(x, 63, 64);
        }
    }
    __syncthreads();
#pragma unroll
    for (int it = 0; it < 4; ++it) {
        int i = t + it * 256;
        if (i < cnt) {
            unsigned int rec = recs[it];
            eidxL[fb[rec >> 16] + lrk[it]] = (unsigned short)(rec & 0xffffu);
        }
    }
    __syncthreads();

    // ---- gather phase: wave w handles nodes ln = w, w+4, ... < 25 ----
    const int half = lane >> 5;              // 0: even edges, 1: odd edges
    const int cl   = lane & 31;              // channel block: ch [cl*8, cl*8+8)
    const uint4* h4 = (const uint4*)h;

    for (int ln = w; ln < NPB; ln += 4) {
        const int node = c * NPB + ln;
        f32x2 acc0 = (f32x2)0.f, acc1 = (f32x2)0.f, acc2 = (f32x2)0.f, acc3 = (f32x2)0.f;
#pragma unroll
        for (int r = 0; r < 3; ++r) {
            int key = 3 * ln + r;
            int dg = fh[key];
            int st = fb[key];
            int end = st + dg;
            float wgt = 1.0f / (3.0f * (float)(dg > 1 ? dg : 1));
            f32x2 r0 = (f32x2)0.f, r1 = (f32x2)0.f, r2 = (f32x2)0.f, r3 = (f32x2)0.f;

            int k = st;
            for (; k + 8 <= end; k += 8) {
                int s0 = eidxL[k + 0], s1 = eidxL[k + 1], s2 = eidxL[k + 2], s3 = eidxL[k + 3];
                int s4 = eidxL[k + 4], s5 = eidxL[k + 5], s6 = eidxL[k + 6], s7 = eidxL[k + 7];
                pair_acc(h4, s0, s1, half, cl, r0, r1, r2, r3);
                pair_acc(h4, s2, s3, half, cl, r0, r1, r2, r3);
                pair_acc(h4, s4, s5, half, cl, r0, r1, r2, r3);
                pair_acc(h4, s6, s7, half, cl, r0, r1, r2, r3);
            }
            if (k + 4 <= end) {
                int s0 = eidxL[k + 0], s1 = eidxL[k + 1], s2 = eidxL[k + 2], s3 = eidxL[k + 3];
                pair_acc(h4, s0, s1, half, cl, r0, r1, r2, r3);
                pair_acc(h4, s2, s3, half, cl, r0, r1, r2, r3);
                k += 4;
            }
            if (k + 2 <= end) {
                int s0 = eidxL[k + 0], s1 = eidxL[k + 1];
                pair_acc(h4, s0, s1, half, cl, r0, r1, r2, r3);
                k += 2;
            }
            if (k < end) {                   // tail edge: lower half only
                int s0 = eidxL[k];
                if (!half) {
                    uint4 u = h4[(size_t)s0 * 32 + cl];
                    f32x2 v;
                    v.x = __uint_as_float(u.x << 16); v.y = __uint_as_float(u.x & 0xffff0000u); r0 += v;
                    v.x = __uint_as_float(u.y << 16); v.y = __uint_as_float(u.y & 0xffff0000u); r1 += v;
                    v.x = __uint_as_float(u.z << 16); v.y = __uint_as_float(u.z & 0xffff0000u); r2 += v;
                    v.x = __uint_as_float(u.w << 16); v.y = __uint_as_float(u.w & 0xffff0000u); r3 += v;
                }
            }
            acc0 += r0 * wgt;
            acc1 += r1 * wgt;
            acc2 += r2 * wgt;
            acc3 += r3 * wgt;
        }

        // combine even/odd halves
        acc0.x += __shfl_xor(acc0.x, 32, 64); acc0.y += __shfl_xor(acc0.y, 32, 64);
        acc1.x += __shfl_xor(acc1.x, 32, 64); acc1.y += __shfl_xor(acc1.y, 32, 64);
        acc2.x += __shfl_xor(acc2.x, 32, 64); acc2.y += __shfl_xor(acc2.y, 32, 64);
        acc3.x += __shfl_xor(acc3.x, 32, 64); acc3.y += __shfl_xor(acc3.y, 32, 64);

        // ReLU
        acc0.x = fmaxf(acc0.x, 0.f); acc0.y = fmaxf(acc0.y, 0.f);
        acc1.x = fmaxf(acc1.x, 0.f); acc1.y = fmaxf(acc1.y, 0.f);
        acc2.x = fmaxf(acc2.x, 0.f); acc2.y = fmaxf(acc2.y, 0.f);
        acc3.x = fmaxf(acc3.x, 0.f); acc3.y = fmaxf(acc3.y, 0.f);

        // LayerNorm: each 32-lane half holds identical data; reduce in half
        float s  = acc0.x + acc0.y + acc1.x + acc1.y + acc2.x + acc2.y + acc3.x + acc3.y;
        float ss = acc0.x * acc0.x + acc0.y * acc0.y + acc1.x * acc1.x + acc1.y * acc1.y
                 + acc2.x * acc2.x + acc2.y * acc2.y + acc3.x * acc3.x + acc3.y * acc3.y;
#pragma unroll
        for (int o2 = 16; o2 > 0; o2 >>= 1) {
            s  += __shfl_xor(s, o2, 64);
            ss += __shfl_xor(ss, o2, 64);
        }
        float mean = s * (1.0f / D);
        float var  = ss * (1.0f / D) - mean * mean;
        float inv  = rsqrtf(var + LN_EPS);

        if (!half) {
            float4 g1 = ((const float4*)gamma)[cl * 2];
            float4 g2 = ((const float4*)gamma)[cl * 2 + 1];
            float4 b1 = ((const float4*)beta)[cl * 2];
            float4 b2 = ((const float4*)beta)[cl * 2 + 1];
            float4 rv1, rv2;
            rv1.x = (acc0.x - mean) * inv * g1.x + b1.x;
            rv1.y = (acc0.y - mean) * inv * g1.y + b1.y;
            rv1.z = (acc1.x - mean) * inv * g1.z + b1.z;
            rv1.w = (acc1.y - mean) * inv * g1.w + b1.w;
            rv2.x = (acc2.x - mean) * inv * g2.x + b2.x;
            rv2.y = (acc2.y - mean) * inv * g2.y + b2.y;
            rv2.z = (acc3.x - mean) * inv * g2.z + b2.z;
            rv2.w = (acc3.y - mean) * inv * g2.w + b2.w;
            float4* o4 = (float4*)out + (size_t)node * 64 + cl * 2;
            o4[0] = rv1;
            o4[1] = rv2;
        }
    }
}

// ---------------------------------------------------------------------------
extern "C" void kernel_launch(void* const* d_in, const int* in_sizes, int n_in,
                              void* d_out, int out_size, void* d_ws, size_t ws_size,
                              hipStream_t stream) {
    const float* feat  = (const float*)d_in[0];
    const float* W0    = (const float*)d_in[1];
    const float* W1    = (const float*)d_in[2];
    const float* W2    = (const float*)d_in[3];
    // d_in[4..6] = a0,a1,a2: unused — attention weights are exactly 1/3
    const float* gamma = (const float*)d_in[7];
    const float* beta  = (const float*)d_in[8];
    const int* src0 = (const int*)d_in[9];
    const int* dst0 = (const int*)d_in[10];
    const int* src1 = (const int*)d_in[11];
    const int* dst1 = (const int*)d_in[12];
    const int* src2 = (const int*)d_in[13];
    const int* dst2 = (const int*)d_in[14];
    float* out = (float*)d_out;

    // workspace: h bf16[N*D] | Wt bf16[D*D] | flag[4] | csum[1200] |
    // ghist[1.2M] | coarse u32[1.2M]   total ~35.3 MB
    unsigned short* h  = (unsigned short*)d_ws;
    unsigned short* Wt = h + (size_t)N_NODES * D;
    int* flag   = (int*)(Wt + D * D);
    int* csum   = flag + 4;
    int* ghist  = csum + 1200;
    unsigned int* coarse = (unsigned int*)(ghist + GHN);

    k_prep2<<<256 + NBA, 256, 0, stream>>>(W0, W1, W2, Wt, flag,
                                           dst0, dst1, dst2, ghist);
    k_scan_gemm<<<GH_NB + GEMM_NB, 256, 0, stream>>>(ghist, csum, flag, feat, Wt, h);
    k_scatter<<<NBA, 256, 0, stream>>>(src0, dst0, src1, dst1, src2, dst2,
                                       ghist, csum, coarse);
    k_fine_gather<<<NCB, 256, 0, stream>>>(coarse, ghist, csum, h,
                                           gamma, beta, out);
}

// Round 5
// 293.745 us; speedup vs baseline: 1.3272x; 1.3272x over previous
//
#include <hip/hip_runtime.h>

#define N_NODES 50000
#define D       256
#define E_EDGES 400000
#define LN_EPS  1e-5f

// ---- two-level counting sort geometry (bin = dst/25, fineKey = 3*(dst%25)+r) ----
#define NPB     25                                  // nodes per fine bin
#define BPB     (3 * NPB)                           // 75 buckets per bin
#define NCB     (N_NODES / NPB)                     // 2000 fine bins (exact)
#define EPB     4000                                // edges per hist/scatter block
#define RB_PER  (E_EDGES / EPB)                     // 100 blocks per relation
#define NBA     (3 * RB_PER)                        // 300 hist/scatter blocks
#define GHN     (NCB * NBA)                         // 600000 scan elements
#define SC_CH   4096                                // scan chunk (16 ints/thread)
#define GH_NB   ((GHN + SC_CH - 1) / SC_CH)         // 147 scan blocks (= fences)
#define CMAX    1024                                // bin record cap (mean 600, +17 sigma)

#define GB_ROWS 64
#define GEMM_NB ((N_NODES + GB_ROWS - 1) / GB_ROWS) // 782

typedef __attribute__((ext_vector_type(8))) short bf16x8;
typedef __attribute__((ext_vector_type(4))) float f32x4;
typedef __attribute__((ext_vector_type(2))) float f32x2;

__device__ __forceinline__ unsigned short f2bf(float f) {
    unsigned int x = __float_as_uint(f);
    x += 0x7fffu + ((x >> 16) & 1u);     // RNE
    return (unsigned short)(x >> 16);
}
__device__ __forceinline__ unsigned int pack2(float lo, float hi) {
    return (unsigned int)f2bf(lo) | ((unsigned int)f2bf(hi) << 16);
}

// ---------------------------------------------------------------------------
// K1: blocks [0,256): Wt[n][k] = bf16((W0+W1+W2)[k][n]/3) (MFMA B^T) + flag=0
//     blocks [256,556): coarse histogram — LDS atomics over 2000 bins
//     (bin = dst/25; all 3 relations of a node share a bin), write
//     ghist[bin*NBA + blk].  ZERO global atomics, zero fences.
// (softmax of size-1 tensors == 1; softmax([1,1,1]) == exactly 1/3 each)
// ---------------------------------------------------------------------------
__global__ __launch_bounds__(256) void k_prep2(const float* __restrict__ W0,
                                               const float* __restrict__ W1,
                                               const float* __restrict__ W2,
                                               unsigned short* __restrict__ Wt,
                                               int* __restrict__ flag,
                                               const int* __restrict__ dst0,
                                               const int* __restrict__ dst1,
                                               const int* __restrict__ dst2,
                                               int* __restrict__ ghist) {
    __shared__ int hist[NCB];
    const int b = blockIdx.x, t = threadIdx.x;
    if (b < 256) {
        if (b == 0 && t == 0) flag[0] = 0;
        int i = b * 256 + t;                 // i = n*256 + k
        int n = i >> 8, k = i & 255;
        float v = (W0[k * D + n] + W1[k * D + n] + W2[k * D + n]) * (1.0f / 3.0f);
        Wt[i] = f2bf(v);
        return;
    }
    const int hb = b - 256;                  // 0..299
    for (int i = t; i < NCB; i += 256) hist[i] = 0;
    __syncthreads();
    const int r = hb / RB_PER, rb = hb - r * RB_PER;
    const int4* dq = (const int4*)((r == 0) ? dst0 : (r == 1) ? dst1 : dst2);
    const int qb = rb * (EPB / 4);
#pragma unroll
    for (int it = 0; it < 4; ++it) {
        int q = t + it * 256;
        if (q < EPB / 4) {
            int4 d = dq[qb + q];
            atomicAdd(&hist[d.x / NPB], 1);
            atomicAdd(&hist[d.y / NPB], 1);
            atomicAdd(&hist[d.z / NPB], 1);
            atomicAdd(&hist[d.w / NPB], 1);
        }
    }
    __syncthreads();
    for (int i = t; i < NCB; i += 256) ghist[i * NBA + hb] = hist[i];
}

// ---------------------------------------------------------------------------
// K2: blocks [0, GH_NB=147): two-level scan of ghist, 4096 elems/block
//     (16 ints/thread) — chunk-local exclusive values stay in g, chunk bases
//     in csum via the last-finished block.  Consumers: g[j] + csum[j>>12].
//     Only 147 threadfence+atomic releases (was 1172 in R4 — the regression).
//     blocks [GH_NB, +GEMM_NB): MFMA GEMM h = bf16(feat) @ Wt^T with
//     LDS-staged B (R3-proven: K-tiled BK=64, +8 pad, coalesced staging).
// ---------------------------------------------------------------------------
__global__ __launch_bounds__(256, 3) void k_scan_gemm(int* __restrict__ g,
                                                      int* __restrict__ csum,
                                                      int* __restrict__ flag,
                                                      const float* __restrict__ feat,
                                                      const unsigned short* __restrict__ Wt,
                                                      unsigned short* __restrict__ h) {
    __shared__ unsigned short sB[256][72];   // 36864 B: Wt[0:256][k0:k0+64)
    __shared__ unsigned short sAk[64][72];   //  9216 B: bf16 A slice
    __shared__ int wsum[4];
    __shared__ int amLast;
    const int b = blockIdx.x, t = threadIdx.x;
    const int lane = t & 63;

    if (b < GH_NB) {
        const int base = b * SC_CH + t * 16;
        int4 v0 = make_int4(0,0,0,0), v1 = v0, v2 = v0, v3 = v0;
        if (base < GHN) {                    // GHN % 16 == 0 -> all-or-nothing
            v0 = *(const int4*)(g + base);
            v1 = *(const int4*)(g + base + 4);
            v2 = *(const int4*)(g + base + 8);
            v3 = *(const int4*)(g + base + 12);
        }
        int pre[16];
        int run = 0;
        pre[0]=run; run+=v0.x; pre[1]=run; run+=v0.y; pre[2]=run; run+=v0.z; pre[3]=run; run+=v0.w;
        pre[4]=run; run+=v1.x; pre[5]=run; run+=v1.y; pre[6]=run; run+=v1.z; pre[7]=run; run+=v1.w;
        pre[8]=run; run+=v2.x; pre[9]=run; run+=v2.y; pre[10]=run; run+=v2.z; pre[11]=run; run+=v2.w;
        pre[12]=run; run+=v3.x; pre[13]=run; run+=v3.y; pre[14]=run; run+=v3.z; pre[15]=run; run+=v3.w;
        const int T = run;
        int x = T;
#pragma unroll
        for (int o2 = 1; o2 < 64; o2 <<= 1) {
            int y = __shfl_up(x, o2, 64);
            if (lane >= o2) x += y;
        }
        if (lane == 63) wsum[t >> 6] = x;
        const int texcl = x - T;
        __syncthreads();
        int wb = 0;
#pragma unroll
        for (int wi = 0; wi < 4; ++wi)
            if (wi < (t >> 6)) wb += wsum[wi];
        const int ex = wb + texcl;
        if (base < GHN) {
            int4 o4;
            o4 = make_int4(ex+pre[0], ex+pre[1], ex+pre[2], ex+pre[3]);   *(int4*)(g+base)    = o4;
            o4 = make_int4(ex+pre[4], ex+pre[5], ex+pre[6], ex+pre[7]);   *(int4*)(g+base+4)  = o4;
            o4 = make_int4(ex+pre[8], ex+pre[9], ex+pre[10], ex+pre[11]); *(int4*)(g+base+8)  = o4;
            o4 = make_int4(ex+pre[12], ex+pre[13], ex+pre[14], ex+pre[15]);*(int4*)(g+base+12)= o4;
        }
        if (t == 0) csum[b] = wsum[0] + wsum[1] + wsum[2] + wsum[3];
        __threadfence();
        if (t == 0) amLast = (atomicAdd(flag, 1) == GH_NB - 1);
        __syncthreads();
        if (!amLast) return;
        __threadfence();
        // tail: scan the 147 chunk totals (single 256-round)
        int carry = 0;
        for (int r0 = 0; r0 < GH_NB; r0 += 256) {
            int idx = r0 + t;
            int vv = (idx < GH_NB) ? ((volatile int*)csum)[idx] : 0;
            int x2 = vv;
#pragma unroll
            for (int o2 = 1; o2 < 64; o2 <<= 1) {
                int y = __shfl_up(x2, o2, 64);
                if (lane >= o2) x2 += y;
            }
            if (lane == 63) wsum[t >> 6] = x2;
            __syncthreads();
            int wb2 = 0;
#pragma unroll
            for (int wi = 0; wi < 4; ++wi)
                if (wi < (t >> 6)) wb2 += wsum[wi];
            int tot = wsum[0] + wsum[1] + wsum[2] + wsum[3];
            if (idx < GH_NB) csum[idx] = carry + wb2 + x2 - vv;
            carry += tot;
            __syncthreads();
        }
        return;
    }

    // ---- GEMM path: K-tiled, LDS-staged B (R3-proven verbatim) ----
    const int row0 = (b - GH_NB) * GB_ROWS;
    const float4* feat4 = (const float4*)feat;
    const int w  = t >> 6;
    const int lr = lane & 15;
    const int lq = lane >> 4;
    const int ar  = t >> 2, aseg = t & 3;    // A staging: 64 rows x 4 segs

    f32x4 acc[16];
#pragma unroll
    for (int tt = 0; tt < 16; ++tt) acc[tt] = (f32x4){0.f, 0.f, 0.f, 0.f};

#pragma unroll
    for (int ks2 = 0; ks2 < 4; ++ks2) {
        if (ks2) __syncthreads();            // protect prev-tile reads
#pragma unroll
        for (int i = 0; i < 8; ++i) {
            int chunk = i * 256 + t;         // 0..2047
            int n = chunk >> 3, c = chunk & 7;
            uint4 v = *(const uint4*)(Wt + n * 256 + ks2 * 64 + c * 8);
            *(uint4*)&sB[n][c * 8] = v;
        }
        {
            float4 a0 = make_float4(0.f, 0.f, 0.f, 0.f), a1 = a0, a2 = a0, a3 = a0;
            if (row0 + ar < N_NODES) {
                const float4* fp = feat4 + (size_t)(row0 + ar) * 64 + ks2 * 16 + aseg * 4;
                a0 = fp[0]; a1 = fp[1]; a2 = fp[2]; a3 = fp[3];
            }
            uint4 p0, p1;
            p0.x = pack2(a0.x, a0.y); p0.y = pack2(a0.z, a0.w);
            p0.z = pack2(a1.x, a1.y); p0.w = pack2(a1.z, a1.w);
            p1.x = pack2(a2.x, a2.y); p1.y = pack2(a2.z, a2.w);
            p1.z = pack2(a3.x, a3.y); p1.w = pack2(a3.z, a3.w);
            *(uint4*)&sAk[ar][aseg * 16]     = p0;
            *(uint4*)&sAk[ar][aseg * 16 + 8] = p1;
        }
        __syncthreads();
#pragma unroll
        for (int kk = 0; kk < 2; ++kk) {
            bf16x8 af = *(const bf16x8*)&sAk[w * 16 + lr][kk * 32 + lq * 8];
            bf16x8 bfr[16];
#pragma unroll
            for (int tt = 0; tt < 16; ++tt)
                bfr[tt] = *(const bf16x8*)&sB[tt * 16 + lr][kk * 32 + lq * 8];
#pragma unroll
            for (int tt = 0; tt < 16; ++tt)
                acc[tt] = __builtin_amdgcn_mfma_f32_16x16x32_bf16(af, bfr[tt], acc[tt], 0, 0, 0);
        }
    }

    __syncthreads();
    unsigned short* sC = &sB[0][0];          // 64 x 264 = 33792 ushorts <= sB
#pragma unroll
    for (int tt = 0; tt < 16; ++tt) {
#pragma unroll
        for (int j = 0; j < 4; ++j)
            sC[(w * 16 + lq * 4 + j) * 264 + tt * 16 + lr] = f2bf(acc[tt][j]);
    }
    __syncthreads();

#pragma unroll
    for (int i = 0; i < 8; ++i) {
        int c = i * 256 + t;
        int r = c >> 5, cc = c & 31;
        if (row0 + r < N_NODES) {
            uint4 v = *(const uint4*)&sC[r * 264 + cc * 8];
            *(uint4*)(h + (size_t)(row0 + r) * D + cc * 8) = v;
        }
    }
}

// ---------------------------------------------------------------------------
// K3: coarse scatter.  Per-block LDS base table sbase[bin]; LDS atomicAdd
// returns dense global positions.  Record = (fineKey<<16) | src where
// fineKey = 3*(dst%25)+r < 75, src < 65536.  ZERO global atomics.
// ---------------------------------------------------------------------------
__global__ __launch_bounds__(256) void k_scatter(const int* __restrict__ src0,
                                                 const int* __restrict__ dst0,
                                                 const int* __restrict__ src1,
                                                 const int* __restrict__ dst1,
                                                 const int* __restrict__ src2,
                                                 const int* __restrict__ dst2,
                                                 const int* __restrict__ g,
                                                 const int* __restrict__ csum,
                                                 unsigned int* __restrict__ coarse) {
    __shared__ int sbase[NCB];
    const int b = blockIdx.x, t = threadIdx.x;
    for (int i = t; i < NCB; i += 256) {
        int j = i * NBA + b;
        sbase[i] = g[j] + csum[j >> 12];
    }
    __syncthreads();
    const int r = b / RB_PER, rb = b - r * RB_PER;
    const int4* sq = (const int4*)((r == 0) ? src0 : (r == 1) ? src1 : src2);
    const int4* dq = (const int4*)((r == 0) ? dst0 : (r == 1) ? dst1 : dst2);
    const int qb = rb * (EPB / 4);
#pragma unroll
    for (int it = 0; it < 4; ++it) {
        int q = t + it * 256;
        if (q < EPB / 4) {
            int4 s = sq[qb + q];
            int4 d = dq[qb + q];
            int bin, p;
            bin = d.x / NPB; p = atomicAdd(&sbase[bin], 1);
            coarse[p] = ((unsigned)(3 * (d.x - bin * NPB) + r) << 16) | (unsigned)s.x;
            bin = d.y / NPB; p = atomicAdd(&sbase[bin], 1);
            coarse[p] = ((unsigned)(3 * (d.y - bin * NPB) + r) << 16) | (unsigned)s.y;
            bin = d.z / NPB; p = atomicAdd(&sbase[bin], 1);
            coarse[p] = ((unsigned)(3 * (d.z - bin * NPB) + r) << 16) | (unsigned)s.z;
            bin = d.w / NPB; p = atomicAdd(&sbase[bin], 1);
            coarse[p] = ((unsigned)(3 * (d.w - bin * NPB) + r) << 16) | (unsigned)s.w;
        }
    }
}

// ---------------------------------------------------------------------------
// K4: fused fine-CSR + gather + ReLU + LayerNorm (R4 structure, passed).
// One block per fine bin (25 nodes, 75 buckets, ~600 records): CSR in LDS,
// then 4 waves gather the 25 nodes' h rows and write LN output.
// ---------------------------------------------------------------------------
__device__ __forceinline__ void pair_acc(const uint4* __restrict__ h4, int sa, int sb,
                                         int half, int cl,
                                         f32x2& a0, f32x2& a1, f32x2& a2, f32x2& a3) {
    int su = half ? sb : sa;
    uint4 u = h4[(size_t)su * 32 + cl];
    f32x2 v;
    v.x = __uint_as_float(u.x << 16); v.y = __uint_as_float(u.x & 0xffff0000u); a0 += v;
    v.x = __uint_as_float(u.y << 16); v.y = __uint_as_float(u.y & 0xffff0000u); a1 += v;
    v.x = __uint_as_float(u.z << 16); v.y = __uint_as_float(u.z & 0xffff0000u); a2 += v;
    v.x = __uint_as_float(u.w << 16); v.y = __uint_as_float(u.w & 0xffff0000u); a3 += v;
}

__global__ __launch_bounds__(256) void k_fine_gather(const unsigned int* __restrict__ coarse,
                                                     const int* __restrict__ g,
                                                     const int* __restrict__ csum,
                                                     const unsigned short* __restrict__ h,
                                                     const float* __restrict__ gamma,
                                                     const float* __restrict__ beta,
                                                     float* __restrict__ out) {
    __shared__ int fh[80], fb[80];
    __shared__ unsigned short eidxL[CMAX];
    const int c = blockIdx.x, t = threadIdx.x;
    const int lane = t & 63, w = t >> 6;
    const int j0 = c * NBA;
    const int S = g[j0] + csum[j0 >> 12];
    const int E = (c + 1 < NCB) ? (g[j0 + NBA] + csum[(j0 + NBA) >> 12]) : (3 * E_EDGES);
    int cnt = E - S;
    if (cnt > CMAX) cnt = CMAX;              // 17-sigma guard vs LDS overflow
    if (t < 80) fh[t] = 0;
    __syncthreads();

    unsigned int recs[4];
    int lrk[4];
#pragma unroll
    for (int it = 0; it < 4; ++it) {
        int i = t + it * 256;
        recs[it] = 0; lrk[it] = 0;
        if (i < cnt) {
            unsigned int rec = coarse[S + i];
            recs[it] = rec;
            lrk[it] = atomicAdd(&fh[rec >> 16], 1);
        }
    }
    __syncthreads();
    if (t < 64) {                            // wave-0 exclusive scan of 75 counts
        int carry = 0;
        for (int b2 = 0; b2 < BPB; b2 += 64) {
            int idx = b2 + t;
            int v = (idx < BPB) ? fh[idx] : 0;
            int x = v;
#pragma unroll
            for (int o2 = 1; o2 < 64; o2 <<= 1) {
                int y = __shfl_up(x, o2, 64);
                if (t >= o2) x += y;
            }
            if (idx < BPB) fb[idx] = carry + x - v;
            carry += __shfl(x, 63, 64);
        }
    }
    __syncthreads();
#pragma unroll
    for (int it = 0; it < 4; ++it) {
        int i = t + it * 256;
        if (i < cnt) {
            unsigned int rec = recs[it];
            eidxL[fb[rec >> 16] + lrk[it]] = (unsigned short)(rec & 0xffffu);
        }
    }
    __syncthreads();

    // ---- gather phase: wave w handles nodes ln = w, w+4, ... < 25 ----
    const int half = lane >> 5;              // 0: even edges, 1: odd edges
    const int cl   = lane & 31;              // channel block: ch [cl*8, cl*8+8)
    const uint4* h4 = (const uint4*)h;

    for (int ln = w; ln < NPB; ln += 4) {
        const int node = c * NPB + ln;
        f32x2 acc0 = (f32x2)0.f, acc1 = (f32x2)0.f, acc2 = (f32x2)0.f, acc3 = (f32x2)0.f;
#pragma unroll
        for (int r = 0; r < 3; ++r) {
            int key = 3 * ln + r;
            int dg = fh[key];
            int st = fb[key];
            int end = st + dg;
            float wgt = 1.0f / (3.0f * (float)(dg > 1 ? dg : 1));
            f32x2 r0 = (f32x2)0.f, r1 = (f32x2)0.f, r2 = (f32x2)0.f, r3 = (f32x2)0.f;

            int k = st;
            for (; k + 8 <= end; k += 8) {
                int s0 = eidxL[k + 0], s1 = eidxL[k + 1], s2 = eidxL[k + 2], s3 = eidxL[k + 3];
                int s4 = eidxL[k + 4], s5 = eidxL[k + 5], s6 = eidxL[k + 6], s7 = eidxL[k + 7];
                pair_acc(h4, s0, s1, half, cl, r0, r1, r2, r3);
                pair_acc(h4, s2, s3, half, cl, r0, r1, r2, r3);
                pair_acc(h4, s4, s5, half, cl, r0, r1, r2, r3);
                pair_acc(h4, s6, s7, half, cl, r0, r1, r2, r3);
            }
            if (k + 4 <= end) {
                int s0 = eidxL[k + 0], s1 = eidxL[k + 1], s2 = eidxL[k + 2], s3 = eidxL[k + 3];
                pair_acc(h4, s0, s1, half, cl, r0, r1, r2, r3);
                pair_acc(h4, s2, s3, half, cl, r0, r1, r2, r3);
                k += 4;
            }
            if (k + 2 <= end) {
                int s0 = eidxL[k + 0], s1 = eidxL[k + 1];
                pair_acc(h4, s0, s1, half, cl, r0, r1, r2, r3);
                k += 2;
            }
            if (k < end) {                   // tail edge: lower half only
                int s0 = eidxL[k];
                if (!half) {
                    uint4 u = h4[(size_t)s0 * 32 + cl];
                    f32x2 v;
                    v.x = __uint_as_float(u.x << 16); v.y = __uint_as_float(u.x & 0xffff0000u); r0 += v;
                    v.x = __uint_as_float(u.y << 16); v.y = __uint_as_float(u.y & 0xffff0000u); r1 += v;
                    v.x = __uint_as_float(u.z << 16); v.y = __uint_as_float(u.z & 0xffff0000u); r2 += v;
                    v.x = __uint_as_float(u.w << 16); v.y = __uint_as_float(u.w & 0xffff0000u); r3 += v;
                }
            }
            acc0 += r0 * wgt;
            acc1 += r1 * wgt;
            acc2 += r2 * wgt;
            acc3 += r3 * wgt;
        }

        // combine even/odd halves
        acc0.x += __shfl_xor(acc0.x, 32, 64); acc0.y += __shfl_xor(acc0.y, 32, 64);
        acc1.x += __shfl_xor(acc1.x, 32, 64); acc1.y += __shfl_xor(acc1.y, 32, 64);
        acc2.x += __shfl_xor(acc2.x, 32, 64); acc2.y += __shfl_xor(acc2.y, 32, 64);
        acc3.x += __shfl_xor(acc3.x, 32, 64); acc3.y += __shfl_xor(acc3.y, 32, 64);

        // ReLU
        acc0.x = fmaxf(acc0.x, 0.f); acc0.y = fmaxf(acc0.y, 0.f);
        acc1.x = fmaxf(acc1.x, 0.f); acc1.y = fmaxf(acc1.y, 0.f);
        acc2.x = fmaxf(acc2.x, 0.f); acc2.y = fmaxf(acc2.y, 0.f);
        acc3.x = fmaxf(acc3.x, 0.f); acc3.y = fmaxf(acc3.y, 0.f);

        // LayerNorm: each 32-lane half holds identical data; reduce in half
        float s  = acc0.x + acc0.y + acc1.x + acc1.y + acc2.x + acc2.y + acc3.x + acc3.y;
        float ss = acc0.x * acc0.x + acc0.y * acc0.y + acc1.x * acc1.x + acc1.y * acc1.y
                 + acc2.x * acc2.x + acc2.y * acc2.y + acc3.x * acc3.x + acc3.y * acc3.y;
#pragma unroll
        for (int o2 = 16; o2 > 0; o2 >>= 1) {
            s  += __shfl_xor(s, o2, 64);
            ss += __shfl_xor(ss, o2, 64);
        }
        float mean = s * (1.0f / D);
        float var  = ss * (1.0f / D) - mean * mean;
        float inv  = rsqrtf(var + LN_EPS);

        if (!half) {
            float4 g1 = ((const float4*)gamma)[cl * 2];
            float4 g2 = ((const float4*)gamma)[cl * 2 + 1];
            float4 b1 = ((const float4*)beta)[cl * 2];
            float4 b2 = ((const float4*)beta)[cl * 2 + 1];
            float4 rv1, rv2;
            rv1.x = (acc0.x - mean) * inv * g1.x + b1.x;
            rv1.y = (acc0.y - mean) * inv * g1.y + b1.y;
            rv1.z = (acc1.x - mean) * inv * g1.z + b1.z;
            rv1.w = (acc1.y - mean) * inv * g1.w + b1.w;
            rv2.x = (acc2.x - mean) * inv * g2.x + b2.x;
            rv2.y = (acc2.y - mean) * inv * g2.y + b2.y;
            rv2.z = (acc3.x - mean) * inv * g2.z + b2.z;
            rv2.w = (acc3.y - mean) * inv * g2.w + b2.w;
            float4* o4 = (float4*)out + (size_t)node * 64 + cl * 2;
            o4[0] = rv1;
            o4[1] = rv2;
        }
    }
}

// ---------------------------------------------------------------------------
extern "C" void kernel_launch(void* const* d_in, const int* in_sizes, int n_in,
                              void* d_out, int out_size, void* d_ws, size_t ws_size,
                              hipStream_t stream) {
    const float* feat  = (const float*)d_in[0];
    const float* W0    = (const float*)d_in[1];
    const float* W1    = (const float*)d_in[2];
    const float* W2    = (const float*)d_in[3];
    // d_in[4..6] = a0,a1,a2: unused — attention weights are exactly 1/3
    const float* gamma = (const float*)d_in[7];
    const float* beta  = (const float*)d_in[8];
    const int* src0 = (const int*)d_in[9];
    const int* dst0 = (const int*)d_in[10];
    const int* src1 = (const int*)d_in[11];
    const int* dst1 = (const int*)d_in[12];
    const int* src2 = (const int*)d_in[13];
    const int* dst2 = (const int*)d_in[14];
    float* out = (float*)d_out;

    // workspace: h bf16[N*D] | Wt bf16[D*D] | flag[4] | csum[160] |
    // ghist[600000] | coarse u32[1.2M]   total ~33 MB
    unsigned short* h  = (unsigned short*)d_ws;
    unsigned short* Wt = h + (size_t)N_NODES * D;
    int* flag   = (int*)(Wt + D * D);
    int* csum   = flag + 4;
    int* ghist  = csum + 160;
    unsigned int* coarse = (unsigned int*)(ghist + GHN);

    k_prep2<<<256 + NBA, 256, 0, stream>>>(W0, W1, W2, Wt, flag,
                                           dst0, dst1, dst2, ghist);
    k_scan_gemm<<<GH_NB + GEMM_NB, 256, 0, stream>>>(ghist, csum, flag, feat, Wt, h);
    k_scatter<<<NBA, 256, 0, stream>>>(src0, dst0, src1, dst1, src2, dst2,
                                       ghist, csum, coarse);
    k_fine_gather<<<NCB, 256, 0, stream>>>(coarse, ghist, csum, h,
                                           gamma, beta, out);
}